// Round 4
// baseline (665.960 us; speedup 1.0000x reference)
//
#include <hip/hip_runtime.h>
#include <hip/hip_bf16.h>

// Problem constants (match reference)
#define NN 100000   // nodes
#define NE 640000   // edges
#define NG 64       // graphs
#define BN_EPS 1e-5f

#define BS 256      // block size
#define SCAN_BS 1024
#define NB_SCAN ((NN + SCAN_BS - 1) / SCAN_BS)   // 98
#define PNPB 2048   // nodes per block in pool

typedef __attribute__((ext_vector_type(8))) unsigned short ushort8_t;
typedef __attribute__((ext_vector_type(4))) unsigned short ushort4_t;

static inline int cdiv(long long a, int b) { return (int)((a + b - 1) / b); }

__device__ __forceinline__ float bf2f(unsigned short u) {
    union { unsigned int i; float f; } c; c.i = ((unsigned int)u) << 16; return c.f;
}
__device__ __forceinline__ unsigned short f2bf(float f) {   // RNE
    unsigned int u = __float_as_uint(f);
    u += 0x7fffu + ((u >> 16) & 1u);
    return (unsigned short)(u >> 16);
}

// ---------------- degree: deg[s] += 1 for non-self-loop edges ----------------
__global__ void deg_kernel(const int* __restrict__ src, const int* __restrict__ dst,
                           float* __restrict__ deg, int E) {
    int e = blockIdx.x * blockDim.x + threadIdx.x;
    if (e >= E) return;
    int s = src[e], d = dst[e];
    if (s != d) unsafeAtomicAdd(&deg[s], 1.0f);
}

// ---- edge weights + CSR histogram: w[e] = -dinv[src]*dinv[dst]; cnt_n[dst]++ if w!=0 ----
__global__ void wgt_hist_kernel(const int* __restrict__ src, const int* __restrict__ dst,
                                const float* __restrict__ deg, float* __restrict__ w,
                                int* __restrict__ cnt_n, int E) {
    int e = blockIdx.x * blockDim.x + threadIdx.x;
    if (e >= E) return;
    int s = src[e], d = dst[e];
    float wv = 0.0f;
    if (s != d) {
        float ds_ = deg[s], dd = deg[d];
        float a = ds_ > 0.0f ? rsqrtf(ds_) : 0.0f;
        float b = dd  > 0.0f ? rsqrtf(dd)  : 0.0f;
        wv = -a * b;
    }
    w[e] = wv;
    if (wv != 0.0f) atomicAdd(&cnt_n[d], 1);
}

// ---------------- 3-kernel exclusive scan of cnt_n -> row_start ----------------
__global__ void scan1_kernel(const int* __restrict__ cnt, int* __restrict__ excl,
                             int* __restrict__ bsum, int N) {
    __shared__ int s[SCAN_BS];
    int t = threadIdx.x;
    int i = blockIdx.x * SCAN_BS + t;
    int v = (i < N) ? cnt[i] : 0;
    s[t] = v;
    __syncthreads();
    for (int off = 1; off < SCAN_BS; off <<= 1) {
        int add = (t >= off) ? s[t - off] : 0;
        __syncthreads();
        s[t] += add;
        __syncthreads();
    }
    if (i < N) excl[i] = s[t] - v;   // exclusive
    if (t == SCAN_BS - 1) bsum[blockIdx.x] = s[t];
}

__global__ void scan2_kernel(int* __restrict__ bsum, int* __restrict__ total, int NB) {
    __shared__ int s[128];
    int t = threadIdx.x;
    int v = (t < NB) ? bsum[t] : 0;
    s[t] = v;
    __syncthreads();
    for (int off = 1; off < 128; off <<= 1) {
        int add = (t >= off) ? s[t - off] : 0;
        __syncthreads();
        s[t] += add;
        __syncthreads();
    }
    if (t < NB) bsum[t] = s[t] - v;  // exclusive
    if (t == 127) *total = s[127];
}

__global__ void scan3_kernel(int* __restrict__ excl, const int* __restrict__ bsum, int N) {
    int i = blockIdx.x * blockDim.x + threadIdx.x;
    if (i < N) excl[i] += bsum[i >> 10];   // SCAN_BS = 1024
}

// ---------------- scatter edges into CSR slots ----------------
__global__ void scatter_kernel(const int* __restrict__ src, const int* __restrict__ dst,
                               const float* __restrict__ w, const int* __restrict__ row_start,
                               int* __restrict__ fill, int* __restrict__ col,
                               float* __restrict__ val, int E) {
    int e = blockIdx.x * blockDim.x + threadIdx.x;
    if (e >= E) return;
    float wv = w[e];
    if (wv == 0.0f) return;
    int d = dst[e];
    int pos = row_start[d] + atomicAdd(&fill[d], 1);
    col[pos] = src[e];
    val[pos] = wv;
}

// ------------- tiled gemm3: Ubf = bf16(x@W2), T = x@W1, S = x@(W0-W2) -------------
// W layout: [3][FI][FO] row-major.
// Block: 256 threads; thread = (cg = col group of 4, ng = node group of 4).
template <int FI, int FO, int KT>
__global__ __launch_bounds__(256) void gemm3t_kernel(
        const float* __restrict__ x, const float* __restrict__ W,
        float* __restrict__ T, float* __restrict__ S,
        unsigned short* __restrict__ Ubf, int N) {
    constexpr int CG  = FO / 4;        // col groups per node
    constexpr int NGB = 256 / CG;      // node groups per block
    constexpr int NPB = NGB * 4;       // nodes per block
    constexpr int XST = NPB + 4;       // x_lds row stride (floats)
    __shared__ float x_lds[KT * XST];
    __shared__ float w_lds[3 * KT * FO];

    const int t  = threadIdx.x;
    const int cg = t % CG;
    const int ng = t / CG;
    const int n0 = blockIdx.x * NPB;

    float4 acc[3][4];
#pragma unroll
    for (int m = 0; m < 3; m++)
#pragma unroll
        for (int nn = 0; nn < 4; nn++) acc[m][nn] = make_float4(0.f, 0.f, 0.f, 0.f);

    for (int kc = 0; kc < FI / KT; kc++) {
        __syncthreads();
        // ---- stage x chunk (global float4 read -> transposed scalar LDS writes) ----
        constexpr int XQ4 = NPB * KT / 4;
        for (int q = t; q < XQ4; q += 256) {
            int i  = q / (KT / 4);            // node within tile
            int j4 = (q % (KT / 4)) * 4;      // k within chunk
            float4 v = make_float4(0.f, 0.f, 0.f, 0.f);
            if (n0 + i < N)
                v = *(const float4*)(x + (size_t)(n0 + i) * FI + kc * KT + j4);
            x_lds[(j4 + 0) * XST + i] = v.x;
            x_lds[(j4 + 1) * XST + i] = v.y;
            x_lds[(j4 + 2) * XST + i] = v.z;
            x_lds[(j4 + 3) * XST + i] = v.w;
        }
        // ---- stage W chunk (direct copy, coalesced float4) ----
        constexpr int WQ4 = 3 * KT * FO / 4;
        for (int q = t; q < WQ4; q += 256) {
            int qq = q * 4;
            int m  = qq / (KT * FO);
            int r  = qq % (KT * FO);
            float4 v = *(const float4*)(W + (size_t)(m * FI + kc * KT) * FO + r);
            *(float4*)&w_lds[m * KT * FO + r] = v;
        }
        __syncthreads();
        // ---- compute: per k, 4 ds_read_b128 + 48 FMAs ----
#pragma unroll 4
        for (int kk = 0; kk < KT; kk++) {
            const float4 xv = *(const float4*)&x_lds[kk * XST + 4 * ng];
            const float4 w0 = *(const float4*)&w_lds[(0 * KT + kk) * FO + 4 * cg];
            const float4 w1 = *(const float4*)&w_lds[(1 * KT + kk) * FO + 4 * cg];
            const float4 w2 = *(const float4*)&w_lds[(2 * KT + kk) * FO + 4 * cg];
            const float xs[4] = {xv.x, xv.y, xv.z, xv.w};
#pragma unroll
            for (int nn = 0; nn < 4; nn++) {
                float xn = xs[nn];
                acc[0][nn].x = fmaf(xn, w0.x, acc[0][nn].x);
                acc[0][nn].y = fmaf(xn, w0.y, acc[0][nn].y);
                acc[0][nn].z = fmaf(xn, w0.z, acc[0][nn].z);
                acc[0][nn].w = fmaf(xn, w0.w, acc[0][nn].w);
                acc[1][nn].x = fmaf(xn, w1.x, acc[1][nn].x);
                acc[1][nn].y = fmaf(xn, w1.y, acc[1][nn].y);
                acc[1][nn].z = fmaf(xn, w1.z, acc[1][nn].z);
                acc[1][nn].w = fmaf(xn, w1.w, acc[1][nn].w);
                acc[2][nn].x = fmaf(xn, w2.x, acc[2][nn].x);
                acc[2][nn].y = fmaf(xn, w2.y, acc[2][nn].y);
                acc[2][nn].z = fmaf(xn, w2.z, acc[2][nn].z);
                acc[2][nn].w = fmaf(xn, w2.w, acc[2][nn].w);
            }
        }
    }
    // ---- store T = a1 (fp32), S = a0 - a2 (fp32), Ubf = bf16(a2) ----
#pragma unroll
    for (int nn = 0; nn < 4; nn++) {
        int n = n0 + 4 * ng + nn;
        if (n >= N) continue;
        size_t o = (size_t)n * FO + 4 * cg;
        *(float4*)(T + o) = acc[1][nn];
        float4 s4;
        s4.x = acc[0][nn].x - acc[2][nn].x;
        s4.y = acc[0][nn].y - acc[2][nn].y;
        s4.z = acc[0][nn].z - acc[2][nn].z;
        s4.w = acc[0][nn].w - acc[2][nn].w;
        *(float4*)(S + o) = s4;
        ushort4_t ub;
        ub.x = f2bf(acc[2][nn].x);
        ub.y = f2bf(acc[2][nn].y);
        ub.z = f2bf(acc[2][nn].z);
        ub.w = f2bf(acc[2][nn].w);
        *(ushort4_t*)(Ubf + o) = ub;
    }
}

// ---- propA_bf: Obf[i] = bf16( T[i] + 2 * sum_p val[p]*Ubf[col[p]] ) ----
// One wave per row. lane = es*LPR + f8 : f8 picks 8 features, es an edge slot.
template <int FO>
__global__ __launch_bounds__(256) void propA_bf_kernel(
        const unsigned short* __restrict__ Ubf, const float* __restrict__ T,
        const int* __restrict__ rs, const int* __restrict__ col,
        const float* __restrict__ val, unsigned short* __restrict__ Obf, int N) {
    constexpr int LPR = FO / 8;      // lanes along feature dim
    constexpr int ES  = 64 / LPR;    // edge slots
    const int lane = threadIdx.x & 63;
    const int i = blockIdx.x * (blockDim.x >> 6) + (threadIdx.x >> 6);
    if (i >= N) return;
    const int f8 = lane % LPR;
    const int es = lane / LPR;
    const int beg = rs[i], end = rs[i + 1];
    float acc[8] = {0.f, 0.f, 0.f, 0.f, 0.f, 0.f, 0.f, 0.f};
    for (int p = beg + es; p < end; p += ES) {
        float wv = val[p];
        int s = col[p];
        ushort8_t u = *(const ushort8_t*)(Ubf + (size_t)s * FO + f8 * 8);
#pragma unroll
        for (int j = 0; j < 8; j++) acc[j] = fmaf(wv, bf2f(u[j]), acc[j]);
    }
#pragma unroll
    for (int mk = LPR; mk < 64; mk <<= 1)
#pragma unroll
        for (int j = 0; j < 8; j++) acc[j] += __shfl_xor(acc[j], mk, 64);
    if (es == 0) {
        const float* tr = T + (size_t)i * FO + f8 * 8;
        float4 t0 = *(const float4*)(tr);
        float4 t1 = *(const float4*)(tr + 4);
        ushort8_t o;
        o[0] = f2bf(t0.x + 2.f * acc[0]);
        o[1] = f2bf(t0.y + 2.f * acc[1]);
        o[2] = f2bf(t0.z + 2.f * acc[2]);
        o[3] = f2bf(t0.w + 2.f * acc[3]);
        o[4] = f2bf(t1.x + 2.f * acc[4]);
        o[5] = f2bf(t1.y + 2.f * acc[5]);
        o[6] = f2bf(t1.z + 2.f * acc[6]);
        o[7] = f2bf(t1.w + 2.f * acc[7]);
        *(ushort8_t*)(Obf + (size_t)i * FO + f8 * 8) = o;
    }
}

// ---- propC_bf: h[i] = leaky_relu(BN(S[i] + sum_p val[p]*Bbf[col[p]] + b))  (h may == S) ----
template <int FO>
__global__ __launch_bounds__(256) void propC_bf_kernel(
        const unsigned short* __restrict__ Bbf, const float* __restrict__ S,
        const int* __restrict__ rs, const int* __restrict__ col,
        const float* __restrict__ val,
        const float* __restrict__ b, const float* __restrict__ g,
        const float* __restrict__ be, const float* __restrict__ m,
        const float* __restrict__ vv, float* __restrict__ h, int N) {
    constexpr int LPR = FO / 8;
    constexpr int ES  = 64 / LPR;
    const int lane = threadIdx.x & 63;
    const int i = blockIdx.x * (blockDim.x >> 6) + (threadIdx.x >> 6);
    if (i >= N) return;
    const int f8 = lane % LPR;
    const int es = lane / LPR;
    const int beg = rs[i], end = rs[i + 1];
    float acc[8] = {0.f, 0.f, 0.f, 0.f, 0.f, 0.f, 0.f, 0.f};
    for (int p = beg + es; p < end; p += ES) {
        float wv = val[p];
        int s = col[p];
        ushort8_t u = *(const ushort8_t*)(Bbf + (size_t)s * FO + f8 * 8);
#pragma unroll
        for (int j = 0; j < 8; j++) acc[j] = fmaf(wv, bf2f(u[j]), acc[j]);
    }
#pragma unroll
    for (int mk = LPR; mk < 64; mk <<= 1)
#pragma unroll
        for (int j = 0; j < 8; j++) acc[j] += __shfl_xor(acc[j], mk, 64);
    if (es == 0) {
        const float* sr = S + (size_t)i * FO + f8 * 8;
        float4 s0 = *(const float4*)(sr);
        float4 s1 = *(const float4*)(sr + 4);
        float res[8] = {s0.x, s0.y, s0.z, s0.w, s1.x, s1.y, s1.z, s1.w};
        float out[8];
#pragma unroll
        for (int j = 0; j < 8; j++) {
            int f = f8 * 8 + j;
            float A = g[f] * rsqrtf(vv[f] + BN_EPS);
            float B = be[f] - (m[f] - b[f]) * A;
            float y = (res[j] + acc[j]) * A + B;
            out[j] = y > 0.0f ? y : 0.01f * y;
        }
        float* hr = h + (size_t)i * FO + f8 * 8;
        *(float4*)(hr)     = make_float4(out[0], out[1], out[2], out[3]);
        *(float4*)(hr + 4) = make_float4(out[4], out[5], out[6], out[7]);
    }
}

// ---------------- mean pool: register accum + LDS table + few global atomics ----------------
__global__ void pool2_kernel(const float* __restrict__ h, const int* __restrict__ batch,
                             float* __restrict__ pool, float* __restrict__ cnt, int N) {
    __shared__ float sp[NG * 16];
    __shared__ float sc[NG];
    int t = threadIdx.x;
    for (int i = t; i < NG * 16; i += BS) sp[i] = 0.f;
    for (int i = t; i < NG; i += BS) sc[i] = 0.f;
    __syncthreads();
    int f = t & 15, lane = t >> 4;   // 16 lanes x 16 features
    int base = blockIdx.x * PNPB;
    int nEnd = min(base + PNPB, N);
    float acc = 0.f, cacc = 0.f;
    int gcur = -1;
    for (int n = base + lane; n < nEnd; n += 16) {
        int g = batch[n];
        if (g != gcur) {
            if (gcur >= 0) {
                atomicAdd(&sp[gcur * 16 + f], acc);
                if (f == 0) atomicAdd(&sc[gcur], cacc);
            }
            gcur = g; acc = 0.f; cacc = 0.f;
        }
        acc += h[(size_t)n * 16 + f];
        cacc += 1.f;
    }
    if (gcur >= 0) {
        atomicAdd(&sp[gcur * 16 + f], acc);
        if (f == 0) atomicAdd(&sc[gcur], cacc);
    }
    __syncthreads();
    for (int i = t; i < NG * 16; i += BS)
        if (sp[i] != 0.f) unsafeAtomicAdd(&pool[i], sp[i]);
    for (int i = t; i < NG; i += BS)
        if (sc[i] != 0.f) unsafeAtomicAdd(&cnt[i], sc[i]);
}

// ---------------- final linear head ----------------
__global__ void final_kernel(const float* __restrict__ pool, const float* __restrict__ cnt,
                             const float* __restrict__ lw, const float* __restrict__ lb,
                             float* __restrict__ out) {
    int idx = threadIdx.x;
    if (idx >= NG * 2) return;
    int g = idx >> 1;
    int c = idx & 1;
    float inv = 1.0f / fmaxf(cnt[g], 1.0f);
    float acc = 0.0f;
#pragma unroll
    for (int f = 0; f < 16; f++) acc += pool[g * 16 + f] * lw[c * 16 + f];
    out[idx] = acc * inv + lb[c];
}

extern "C" void kernel_launch(void* const* d_in, const int* in_sizes, int n_in,
                              void* d_out, int out_size, void* d_ws, size_t ws_size,
                              hipStream_t stream) {
    const float* x    = (const float*)d_in[0];
    const int*   ei   = (const int*)d_in[1];
    const int*   batch= (const int*)d_in[2];
    const float* W1 = (const float*)d_in[3];
    const float* b1 = (const float*)d_in[4];
    const float* g1 = (const float*)d_in[5];
    const float* be1= (const float*)d_in[6];
    const float* m1 = (const float*)d_in[7];
    const float* v1 = (const float*)d_in[8];
    const float* W2 = (const float*)d_in[9];
    const float* b2 = (const float*)d_in[10];
    const float* g2 = (const float*)d_in[11];
    const float* be2= (const float*)d_in[12];
    const float* m2 = (const float*)d_in[13];
    const float* v2 = (const float*)d_in[14];
    const float* W3 = (const float*)d_in[15];
    const float* b3 = (const float*)d_in[16];
    const float* g3 = (const float*)d_in[17];
    const float* be3= (const float*)d_in[18];
    const float* m3 = (const float*)d_in[19];
    const float* v3 = (const float*)d_in[20];
    const float* lw = (const float*)d_in[21];
    const float* lb = (const float*)d_in[22];

    const int* src = ei;            // edge_index[0]
    const int* dst = ei + NE;       // edge_index[1]

    float* ws = (float*)d_ws;
    // ---- workspace layout (4-byte units, 16B-aligned) ----
    size_t off = 0;
    float* deg   = ws + off; off += NN;
    int*   cnt_n = (int*)(ws + off); off += NN;
    int*   fill  = (int*)(ws + off); off += NN;
    float* pool  = ws + off; off += NG * 16;
    float* cnt   = ws + off; off += NG;
    size_t zero_bytes = off * sizeof(float);       // one memset covers all of the above
    float* w     = ws + off; off += NE;
    int*   rs    = (int*)(ws + off); off += NN + 4;  // row_start [N+1], padded
    int*   col   = (int*)(ws + off); off += NE;
    float* val   = ws + off; off += NE;
    int*   bsum  = (int*)(ws + off); off += 128;
    float* A    = ws + off; off += (size_t)NN * 64;          // T buffers
    float* Bb   = ws + off; off += (size_t)NN * 64;          // S1 / h1
    float* D    = ws + off; off += (size_t)NN * 32;          // S2 / h2
    float* C16  = ws + off; off += (size_t)NN * 16;          // S3 / h3
    unsigned short* Ubf  = (unsigned short*)(ws + off); off += (size_t)NN * 32;  // NN*64 bf16
    unsigned short* Bbbf = (unsigned short*)(ws + off); off += (size_t)NN * 32;  // NN*64 bf16

    hipMemsetAsync(ws, 0, zero_bytes, stream);

    // ---- edge weights + CSR build ----
    deg_kernel<<<cdiv(NE, BS), BS, 0, stream>>>(src, dst, deg, NE);
    wgt_hist_kernel<<<cdiv(NE, BS), BS, 0, stream>>>(src, dst, deg, w, cnt_n, NE);
    scan1_kernel<<<NB_SCAN, SCAN_BS, 0, stream>>>(cnt_n, rs, bsum, NN);
    scan2_kernel<<<1, 128, 0, stream>>>(bsum, rs + NN, NB_SCAN);
    scan3_kernel<<<cdiv(NN, BS), BS, 0, stream>>>(rs, bsum, NN);
    scatter_kernel<<<cdiv(NE, BS), BS, 0, stream>>>(src, dst, w, rs, fill, col, val, NE);

    // ---- layer 1: 128 -> 64 ----
    gemm3t_kernel<128, 64, 32><<<cdiv(NN, 64), 256, 0, stream>>>(x, W1, A, Bb, Ubf, NN);
    propA_bf_kernel<64><<<cdiv(NN, 4), 256, 0, stream>>>(Ubf, A, rs, col, val, Bbbf, NN);
    propC_bf_kernel<64><<<cdiv(NN, 4), 256, 0, stream>>>(Bbbf, Bb, rs, col, val,
                                                         b1, g1, be1, m1, v1, Bb, NN);
    // ---- layer 2: 64 -> 32 ----
    gemm3t_kernel<64, 32, 32><<<cdiv(NN, 128), 256, 0, stream>>>(Bb, W2, A, D, Ubf, NN);
    propA_bf_kernel<32><<<cdiv(NN, 4), 256, 0, stream>>>(Ubf, A, rs, col, val, Bbbf, NN);
    propC_bf_kernel<32><<<cdiv(NN, 4), 256, 0, stream>>>(Bbbf, D, rs, col, val,
                                                         b2, g2, be2, m2, v2, D, NN);
    // ---- layer 3: 32 -> 16 ----
    gemm3t_kernel<32, 16, 32><<<cdiv(NN, 256), 256, 0, stream>>>(D, W3, A, C16, Ubf, NN);
    propA_bf_kernel<16><<<cdiv(NN, 4), 256, 0, stream>>>(Ubf, A, rs, col, val, Bbbf, NN);
    propC_bf_kernel<16><<<cdiv(NN, 4), 256, 0, stream>>>(Bbbf, C16, rs, col, val,
                                                         b3, g3, be3, m3, v3, C16, NN);
    // ---- pool + head ----
    pool2_kernel<<<cdiv(NN, PNPB), BS, 0, stream>>>(C16, batch, pool, cnt, NN);
    final_kernel<<<1, 128, 0, stream>>>(pool, cnt, lw, lb, (float*)d_out);
}

// Round 5
// 523.823 us; speedup vs baseline: 1.2713x; 1.2713x over previous
//
#include <hip/hip_runtime.h>
#include <hip/hip_bf16.h>

// Problem constants (match reference)
#define NN 100000   // nodes
#define NE 640000   // edges
#define NG 64       // graphs
#define BN_EPS 1e-5f

#define BS 256      // block size
#define SCAN_BS 1024
#define NB_SCAN ((NN + SCAN_BS - 1) / SCAN_BS)   // 98
#define PNPB 2048   // nodes per block in pool

typedef __attribute__((ext_vector_type(8))) unsigned short ushort8_t;
typedef __attribute__((ext_vector_type(4))) unsigned short ushort4_t;

static inline int cdiv(long long a, int b) { return (int)((a + b - 1) / b); }

__device__ __forceinline__ float bf2f(unsigned short u) {
    union { unsigned int i; float f; } c; c.i = ((unsigned int)u) << 16; return c.f;
}
__device__ __forceinline__ unsigned short f2bf(float f) {   // RNE
    unsigned int u = __float_as_uint(f);
    u += 0x7fffu + ((u >> 16) & 1u);
    return (unsigned short)(u >> 16);
}

// ---------------- degree: deg[s] += 1 for non-self-loop edges ----------------
__global__ void deg_kernel(const int* __restrict__ src, const int* __restrict__ dst,
                           float* __restrict__ deg, int E) {
    int e = blockIdx.x * blockDim.x + threadIdx.x;
    if (e >= E) return;
    int s = src[e], d = dst[e];
    if (s != d) unsafeAtomicAdd(&deg[s], 1.0f);
}

// ---- edge weights + CSR histogram: w[e] = -dinv[src]*dinv[dst]; cnt_n[dst]++ if w!=0 ----
__global__ void wgt_hist_kernel(const int* __restrict__ src, const int* __restrict__ dst,
                                const float* __restrict__ deg, float* __restrict__ w,
                                int* __restrict__ cnt_n, int E) {
    int e = blockIdx.x * blockDim.x + threadIdx.x;
    if (e >= E) return;
    int s = src[e], d = dst[e];
    float wv = 0.0f;
    if (s != d) {
        float ds_ = deg[s], dd = deg[d];
        float a = ds_ > 0.0f ? rsqrtf(ds_) : 0.0f;
        float b = dd  > 0.0f ? rsqrtf(dd)  : 0.0f;
        wv = -a * b;
    }
    w[e] = wv;
    if (wv != 0.0f) atomicAdd(&cnt_n[d], 1);
}

// ---------------- 3-kernel exclusive scan of cnt_n -> row_start ----------------
__global__ void scan1_kernel(const int* __restrict__ cnt, int* __restrict__ excl,
                             int* __restrict__ bsum, int N) {
    __shared__ int s[SCAN_BS];
    int t = threadIdx.x;
    int i = blockIdx.x * SCAN_BS + t;
    int v = (i < N) ? cnt[i] : 0;
    s[t] = v;
    __syncthreads();
    for (int off = 1; off < SCAN_BS; off <<= 1) {
        int add = (t >= off) ? s[t - off] : 0;
        __syncthreads();
        s[t] += add;
        __syncthreads();
    }
    if (i < N) excl[i] = s[t] - v;   // exclusive
    if (t == SCAN_BS - 1) bsum[blockIdx.x] = s[t];
}

__global__ void scan2_kernel(int* __restrict__ bsum, int* __restrict__ total, int NB) {
    __shared__ int s[128];
    int t = threadIdx.x;
    int v = (t < NB) ? bsum[t] : 0;
    s[t] = v;
    __syncthreads();
    for (int off = 1; off < 128; off <<= 1) {
        int add = (t >= off) ? s[t - off] : 0;
        __syncthreads();
        s[t] += add;
        __syncthreads();
    }
    if (t < NB) bsum[t] = s[t] - v;  // exclusive
    if (t == 127) *total = s[127];
}

__global__ void scan3_kernel(int* __restrict__ excl, const int* __restrict__ bsum, int N) {
    int i = blockIdx.x * blockDim.x + threadIdx.x;
    if (i < N) excl[i] += bsum[i >> 10];   // SCAN_BS = 1024
}

// ---------------- scatter edges into CSR slots ----------------
__global__ void scatter_kernel(const int* __restrict__ src, const int* __restrict__ dst,
                               const float* __restrict__ w, const int* __restrict__ row_start,
                               int* __restrict__ fill, int* __restrict__ col,
                               float* __restrict__ val, int E) {
    int e = blockIdx.x * blockDim.x + threadIdx.x;
    if (e >= E) return;
    float wv = w[e];
    if (wv == 0.0f) return;
    int d = dst[e];
    int pos = row_start[d] + atomicAdd(&fill[d], 1);
    col[pos] = src[e];
    val[pos] = wv;
}

// ------------- tiled gemm3: Ubf = bf16(x@W2), T = x@W1, S = x@(W0-W2) -------------
// W layout: [3][FI][FO] row-major.
// Block: 256 threads; thread = (cg = col group of 4, ng = node group of 4).
template <int FI, int FO, int KT>
__global__ __launch_bounds__(256) void gemm3t_kernel(
        const float* __restrict__ x, const float* __restrict__ W,
        float* __restrict__ T, float* __restrict__ S,
        unsigned short* __restrict__ Ubf, int N) {
    constexpr int CG  = FO / 4;        // col groups per node
    constexpr int NGB = 256 / CG;      // node groups per block
    constexpr int NPB = NGB * 4;       // nodes per block
    constexpr int XST = NPB + 4;       // x_lds row stride (floats)
    __shared__ float x_lds[KT * XST];
    __shared__ float w_lds[3 * KT * FO];

    const int t  = threadIdx.x;
    const int cg = t % CG;
    const int ng = t / CG;
    const int n0 = blockIdx.x * NPB;

    float4 acc[3][4];
#pragma unroll
    for (int m = 0; m < 3; m++)
#pragma unroll
        for (int nn = 0; nn < 4; nn++) acc[m][nn] = make_float4(0.f, 0.f, 0.f, 0.f);

    for (int kc = 0; kc < FI / KT; kc++) {
        __syncthreads();
        // ---- stage x chunk (global float4 read -> transposed scalar LDS writes) ----
        constexpr int XQ4 = NPB * KT / 4;
        for (int q = t; q < XQ4; q += 256) {
            int i  = q / (KT / 4);            // node within tile
            int j4 = (q % (KT / 4)) * 4;      // k within chunk
            float4 v = make_float4(0.f, 0.f, 0.f, 0.f);
            if (n0 + i < N)
                v = *(const float4*)(x + (size_t)(n0 + i) * FI + kc * KT + j4);
            x_lds[(j4 + 0) * XST + i] = v.x;
            x_lds[(j4 + 1) * XST + i] = v.y;
            x_lds[(j4 + 2) * XST + i] = v.z;
            x_lds[(j4 + 3) * XST + i] = v.w;
        }
        // ---- stage W chunk (direct copy, coalesced float4) ----
        constexpr int WQ4 = 3 * KT * FO / 4;
        for (int q = t; q < WQ4; q += 256) {
            int qq = q * 4;
            int m  = qq / (KT * FO);
            int r  = qq % (KT * FO);
            float4 v = *(const float4*)(W + (size_t)(m * FI + kc * KT) * FO + r);
            *(float4*)&w_lds[m * KT * FO + r] = v;
        }
        __syncthreads();
        // ---- compute: per k, 4 ds_read_b128 + 48 FMAs ----
#pragma unroll 4
        for (int kk = 0; kk < KT; kk++) {
            const float4 xv = *(const float4*)&x_lds[kk * XST + 4 * ng];
            const float4 w0 = *(const float4*)&w_lds[(0 * KT + kk) * FO + 4 * cg];
            const float4 w1 = *(const float4*)&w_lds[(1 * KT + kk) * FO + 4 * cg];
            const float4 w2 = *(const float4*)&w_lds[(2 * KT + kk) * FO + 4 * cg];
            const float xs[4] = {xv.x, xv.y, xv.z, xv.w};
#pragma unroll
            for (int nn = 0; nn < 4; nn++) {
                float xn = xs[nn];
                acc[0][nn].x = fmaf(xn, w0.x, acc[0][nn].x);
                acc[0][nn].y = fmaf(xn, w0.y, acc[0][nn].y);
                acc[0][nn].z = fmaf(xn, w0.z, acc[0][nn].z);
                acc[0][nn].w = fmaf(xn, w0.w, acc[0][nn].w);
                acc[1][nn].x = fmaf(xn, w1.x, acc[1][nn].x);
                acc[1][nn].y = fmaf(xn, w1.y, acc[1][nn].y);
                acc[1][nn].z = fmaf(xn, w1.z, acc[1][nn].z);
                acc[1][nn].w = fmaf(xn, w1.w, acc[1][nn].w);
                acc[2][nn].x = fmaf(xn, w2.x, acc[2][nn].x);
                acc[2][nn].y = fmaf(xn, w2.y, acc[2][nn].y);
                acc[2][nn].z = fmaf(xn, w2.z, acc[2][nn].z);
                acc[2][nn].w = fmaf(xn, w2.w, acc[2][nn].w);
            }
        }
    }
    // ---- store T = a1 (fp32), S = a0 - a2 (fp32), Ubf = bf16(a2) ----
#pragma unroll
    for (int nn = 0; nn < 4; nn++) {
        int n = n0 + 4 * ng + nn;
        if (n >= N) continue;
        size_t o = (size_t)n * FO + 4 * cg;
        *(float4*)(T + o) = acc[1][nn];
        float4 s4;
        s4.x = acc[0][nn].x - acc[2][nn].x;
        s4.y = acc[0][nn].y - acc[2][nn].y;
        s4.z = acc[0][nn].z - acc[2][nn].z;
        s4.w = acc[0][nn].w - acc[2][nn].w;
        *(float4*)(S + o) = s4;
        ushort4_t ub;
        ub.x = f2bf(acc[2][nn].x);
        ub.y = f2bf(acc[2][nn].y);
        ub.z = f2bf(acc[2][nn].z);
        ub.w = f2bf(acc[2][nn].w);
        *(ushort4_t*)(Ubf + o) = ub;
    }
}

// ---- propA8: Obf[i] = bf16( T[i] + 2 * sum_p val[p]*Ubf[col[p]] ) ----
// Thread per (row, 8-feature chunk); loop over the row's CSR range (R3 structure).
template <int FO>
__global__ void propA8_kernel(const unsigned short* __restrict__ Ubf,
                              const float* __restrict__ T,
                              const int* __restrict__ rs, const int* __restrict__ col,
                              const float* __restrict__ val,
                              unsigned short* __restrict__ Obf, int N) {
    constexpr int PER = FO / 8;
    unsigned idx = blockIdx.x * blockDim.x + threadIdx.x;
    if (idx >= (unsigned)N * PER) return;
    int i = idx / PER;
    int c = (idx & (PER - 1)) * 8;
    int beg = rs[i], end = rs[i + 1];
    float acc[8] = {0.f, 0.f, 0.f, 0.f, 0.f, 0.f, 0.f, 0.f};
    for (int p = beg; p < end; ++p) {
        float wv = val[p];
        int s = col[p];
        ushort8_t u = *(const ushort8_t*)(Ubf + (size_t)s * FO + c);
#pragma unroll
        for (int j = 0; j < 8; j++) acc[j] = fmaf(wv, bf2f(u[j]), acc[j]);
    }
    const float* tr = T + (size_t)i * FO + c;
    float4 t0 = *(const float4*)(tr);
    float4 t1 = *(const float4*)(tr + 4);
    const float ts[8] = {t0.x, t0.y, t0.z, t0.w, t1.x, t1.y, t1.z, t1.w};
    ushort8_t o;
#pragma unroll
    for (int j = 0; j < 8; j++) o[j] = f2bf(ts[j] + 2.f * acc[j]);
    *(ushort8_t*)(Obf + (size_t)i * FO + c) = o;
}

// ---- propC8: h[i] = leaky_relu(BN(S[i] + sum_p val[p]*Bbf[col[p]] + b))  (h may == S) ----
template <int FO>
__global__ void propC8_kernel(const unsigned short* __restrict__ Bbf,
                              const float* __restrict__ S,
                              const int* __restrict__ rs, const int* __restrict__ col,
                              const float* __restrict__ val,
                              const float* __restrict__ b, const float* __restrict__ g,
                              const float* __restrict__ be, const float* __restrict__ m,
                              const float* __restrict__ vv, float* __restrict__ h, int N) {
    constexpr int PER = FO / 8;
    unsigned idx = blockIdx.x * blockDim.x + threadIdx.x;
    if (idx >= (unsigned)N * PER) return;
    int i = idx / PER;
    int c = (idx & (PER - 1)) * 8;
    int beg = rs[i], end = rs[i + 1];
    float acc[8] = {0.f, 0.f, 0.f, 0.f, 0.f, 0.f, 0.f, 0.f};
    for (int p = beg; p < end; ++p) {
        float wv = val[p];
        int s = col[p];
        ushort8_t u = *(const ushort8_t*)(Bbf + (size_t)s * FO + c);
#pragma unroll
        for (int j = 0; j < 8; j++) acc[j] = fmaf(wv, bf2f(u[j]), acc[j]);
    }
    const float* sr = S + (size_t)i * FO + c;
    float4 s0 = *(const float4*)(sr);
    float4 s1 = *(const float4*)(sr + 4);
    const float ss[8] = {s0.x, s0.y, s0.z, s0.w, s1.x, s1.y, s1.z, s1.w};
    float out[8];
#pragma unroll
    for (int j = 0; j < 8; j++) {
        int f = c + j;
        float A = g[f] * rsqrtf(vv[f] + BN_EPS);
        float B = be[f] - (m[f] - b[f]) * A;
        float y = (ss[j] + acc[j]) * A + B;
        out[j] = y > 0.0f ? y : 0.01f * y;
    }
    float* hr = h + (size_t)i * FO + c;
    *(float4*)(hr)     = make_float4(out[0], out[1], out[2], out[3]);
    *(float4*)(hr + 4) = make_float4(out[4], out[5], out[6], out[7]);
}

// ---------------- mean pool: register accum + LDS table + few global atomics ----------------
__global__ void pool2_kernel(const float* __restrict__ h, const int* __restrict__ batch,
                             float* __restrict__ pool, float* __restrict__ cnt, int N) {
    __shared__ float sp[NG * 16];
    __shared__ float sc[NG];
    int t = threadIdx.x;
    for (int i = t; i < NG * 16; i += BS) sp[i] = 0.f;
    for (int i = t; i < NG; i += BS) sc[i] = 0.f;
    __syncthreads();
    int f = t & 15, lane = t >> 4;   // 16 lanes x 16 features
    int base = blockIdx.x * PNPB;
    int nEnd = min(base + PNPB, N);
    float acc = 0.f, cacc = 0.f;
    int gcur = -1;
    for (int n = base + lane; n < nEnd; n += 16) {
        int g = batch[n];
        if (g != gcur) {
            if (gcur >= 0) {
                atomicAdd(&sp[gcur * 16 + f], acc);
                if (f == 0) atomicAdd(&sc[gcur], cacc);
            }
            gcur = g; acc = 0.f; cacc = 0.f;
        }
        acc += h[(size_t)n * 16 + f];
        cacc += 1.f;
    }
    if (gcur >= 0) {
        atomicAdd(&sp[gcur * 16 + f], acc);
        if (f == 0) atomicAdd(&sc[gcur], cacc);
    }
    __syncthreads();
    for (int i = t; i < NG * 16; i += BS)
        if (sp[i] != 0.f) unsafeAtomicAdd(&pool[i], sp[i]);
    for (int i = t; i < NG; i += BS)
        if (sc[i] != 0.f) unsafeAtomicAdd(&cnt[i], sc[i]);
}

// ---------------- final linear head ----------------
__global__ void final_kernel(const float* __restrict__ pool, const float* __restrict__ cnt,
                             const float* __restrict__ lw, const float* __restrict__ lb,
                             float* __restrict__ out) {
    int idx = threadIdx.x;
    if (idx >= NG * 2) return;
    int g = idx >> 1;
    int c = idx & 1;
    float inv = 1.0f / fmaxf(cnt[g], 1.0f);
    float acc = 0.0f;
#pragma unroll
    for (int f = 0; f < 16; f++) acc += pool[g * 16 + f] * lw[c * 16 + f];
    out[idx] = acc * inv + lb[c];
}

extern "C" void kernel_launch(void* const* d_in, const int* in_sizes, int n_in,
                              void* d_out, int out_size, void* d_ws, size_t ws_size,
                              hipStream_t stream) {
    const float* x    = (const float*)d_in[0];
    const int*   ei   = (const int*)d_in[1];
    const int*   batch= (const int*)d_in[2];
    const float* W1 = (const float*)d_in[3];
    const float* b1 = (const float*)d_in[4];
    const float* g1 = (const float*)d_in[5];
    const float* be1= (const float*)d_in[6];
    const float* m1 = (const float*)d_in[7];
    const float* v1 = (const float*)d_in[8];
    const float* W2 = (const float*)d_in[9];
    const float* b2 = (const float*)d_in[10];
    const float* g2 = (const float*)d_in[11];
    const float* be2= (const float*)d_in[12];
    const float* m2 = (const float*)d_in[13];
    const float* v2 = (const float*)d_in[14];
    const float* W3 = (const float*)d_in[15];
    const float* b3 = (const float*)d_in[16];
    const float* g3 = (const float*)d_in[17];
    const float* be3= (const float*)d_in[18];
    const float* m3 = (const float*)d_in[19];
    const float* v3 = (const float*)d_in[20];
    const float* lw = (const float*)d_in[21];
    const float* lb = (const float*)d_in[22];

    const int* src = ei;            // edge_index[0]
    const int* dst = ei + NE;       // edge_index[1]

    float* ws = (float*)d_ws;
    // ---- workspace layout (4-byte units, 16B-aligned) ----
    size_t off = 0;
    float* deg   = ws + off; off += NN;
    int*   cnt_n = (int*)(ws + off); off += NN;
    int*   fill  = (int*)(ws + off); off += NN;
    float* pool  = ws + off; off += NG * 16;
    float* cnt   = ws + off; off += NG;
    size_t zero_bytes = off * sizeof(float);       // one memset covers all of the above
    float* w     = ws + off; off += NE;
    int*   rs    = (int*)(ws + off); off += NN + 4;  // row_start [N+1], padded
    int*   col   = (int*)(ws + off); off += NE;
    float* val   = ws + off; off += NE;
    int*   bsum  = (int*)(ws + off); off += 128;
    float* A    = ws + off; off += (size_t)NN * 64;          // T buffers
    float* Bb   = ws + off; off += (size_t)NN * 64;          // S1 / h1
    float* D    = ws + off; off += (size_t)NN * 32;          // S2 / h2
    float* C16  = ws + off; off += (size_t)NN * 16;          // S3 / h3
    unsigned short* Ubf  = (unsigned short*)(ws + off); off += (size_t)NN * 32;  // NN*64 bf16
    unsigned short* Bbbf = (unsigned short*)(ws + off); off += (size_t)NN * 32;  // NN*64 bf16

    hipMemsetAsync(ws, 0, zero_bytes, stream);

    // ---- edge weights + CSR build ----
    deg_kernel<<<cdiv(NE, BS), BS, 0, stream>>>(src, dst, deg, NE);
    wgt_hist_kernel<<<cdiv(NE, BS), BS, 0, stream>>>(src, dst, deg, w, cnt_n, NE);
    scan1_kernel<<<NB_SCAN, SCAN_BS, 0, stream>>>(cnt_n, rs, bsum, NN);
    scan2_kernel<<<1, 128, 0, stream>>>(bsum, rs + NN, NB_SCAN);
    scan3_kernel<<<cdiv(NN, BS), BS, 0, stream>>>(rs, bsum, NN);
    scatter_kernel<<<cdiv(NE, BS), BS, 0, stream>>>(src, dst, w, rs, fill, col, val, NE);

    // ---- layer 1: 128 -> 64 ----
    gemm3t_kernel<128, 64, 32><<<cdiv(NN, 64), 256, 0, stream>>>(x, W1, A, Bb, Ubf, NN);
    propA8_kernel<64><<<cdiv((long long)NN * 8, BS), BS, 0, stream>>>(Ubf, A, rs, col, val, Bbbf, NN);
    propC8_kernel<64><<<cdiv((long long)NN * 8, BS), BS, 0, stream>>>(Bbbf, Bb, rs, col, val,
                                                                      b1, g1, be1, m1, v1, Bb, NN);
    // ---- layer 2: 64 -> 32 ----
    gemm3t_kernel<64, 32, 32><<<cdiv(NN, 128), 256, 0, stream>>>(Bb, W2, A, D, Ubf, NN);
    propA8_kernel<32><<<cdiv((long long)NN * 4, BS), BS, 0, stream>>>(Ubf, A, rs, col, val, Bbbf, NN);
    propC8_kernel<32><<<cdiv((long long)NN * 4, BS), BS, 0, stream>>>(Bbbf, D, rs, col, val,
                                                                      b2, g2, be2, m2, v2, D, NN);
    // ---- layer 3: 32 -> 16 ----
    gemm3t_kernel<32, 16, 32><<<cdiv(NN, 256), 256, 0, stream>>>(D, W3, A, C16, Ubf, NN);
    propA8_kernel<16><<<cdiv((long long)NN * 2, BS), BS, 0, stream>>>(Ubf, A, rs, col, val, Bbbf, NN);
    propC8_kernel<16><<<cdiv((long long)NN * 2, BS), BS, 0, stream>>>(Bbbf, C16, rs, col, val,
                                                                      b3, g3, be3, m3, v3, C16, NN);
    // ---- pool + head ----
    pool2_kernel<<<cdiv(NN, PNPB), BS, 0, stream>>>(C16, batch, pool, cnt, NN);
    final_kernel<<<1, 128, 0, stream>>>(pool, cnt, lw, lb, (float*)d_out);
}

// Round 6
// 499.494 us; speedup vs baseline: 1.3333x; 1.0487x over previous
//
#include <hip/hip_runtime.h>
#include <hip/hip_bf16.h>

// Problem constants (match reference)
#define NN 100000   // nodes
#define NE 640000   // edges
#define NG 64       // graphs
#define BN_EPS 1e-5f

#define BS 256      // block size
#define SCAN_BS 1024
#define NB_SCAN ((NN + SCAN_BS - 1) / SCAN_BS)   // 98
#define PNPB 2048   // nodes per block in pool

typedef __attribute__((ext_vector_type(8))) unsigned short ushort8_t;
typedef __attribute__((ext_vector_type(4))) unsigned short ushort4_t;
typedef __attribute__((ext_vector_type(8))) short bf16x8_t;    // MFMA A/B frag (4 VGPR)
typedef __attribute__((ext_vector_type(4))) float floatx4_t;   // MFMA C/D frag

static inline int cdiv(long long a, int b) { return (int)((a + b - 1) / b); }

__device__ __forceinline__ float bf2f(unsigned short u) {
    union { unsigned int i; float f; } c; c.i = ((unsigned int)u) << 16; return c.f;
}
__device__ __forceinline__ unsigned short f2bf(float f) {   // RNE
    unsigned int u = __float_as_uint(f);
    u += 0x7fffu + ((u >> 16) & 1u);
    return (unsigned short)(u >> 16);
}

// ---------------- degree: deg[s] += 1 for non-self-loop edges ----------------
__global__ void deg_kernel(const int* __restrict__ src, const int* __restrict__ dst,
                           float* __restrict__ deg, int E) {
    int e = blockIdx.x * blockDim.x + threadIdx.x;
    if (e >= E) return;
    int s = src[e], d = dst[e];
    if (s != d) unsafeAtomicAdd(&deg[s], 1.0f);
}

// ---- edge weights + CSR histogram: w[e] = -dinv[src]*dinv[dst]; cnt_n[dst]++ if w!=0 ----
__global__ void wgt_hist_kernel(const int* __restrict__ src, const int* __restrict__ dst,
                                const float* __restrict__ deg, float* __restrict__ w,
                                int* __restrict__ cnt_n, int E) {
    int e = blockIdx.x * blockDim.x + threadIdx.x;
    if (e >= E) return;
    int s = src[e], d = dst[e];
    float wv = 0.0f;
    if (s != d) {
        float ds_ = deg[s], dd = deg[d];
        float a = ds_ > 0.0f ? rsqrtf(ds_) : 0.0f;
        float b = dd  > 0.0f ? rsqrtf(dd)  : 0.0f;
        wv = -a * b;
    }
    w[e] = wv;
    if (wv != 0.0f) atomicAdd(&cnt_n[d], 1);
}

// ---------------- 3-kernel exclusive scan of cnt_n -> row_start ----------------
__global__ void scan1_kernel(const int* __restrict__ cnt, int* __restrict__ excl,
                             int* __restrict__ bsum, int N) {
    __shared__ int s[SCAN_BS];
    int t = threadIdx.x;
    int i = blockIdx.x * SCAN_BS + t;
    int v = (i < N) ? cnt[i] : 0;
    s[t] = v;
    __syncthreads();
    for (int off = 1; off < SCAN_BS; off <<= 1) {
        int add = (t >= off) ? s[t - off] : 0;
        __syncthreads();
        s[t] += add;
        __syncthreads();
    }
    if (i < N) excl[i] = s[t] - v;   // exclusive
    if (t == SCAN_BS - 1) bsum[blockIdx.x] = s[t];
}

__global__ void scan2_kernel(int* __restrict__ bsum, int* __restrict__ total, int NB) {
    __shared__ int s[128];
    int t = threadIdx.x;
    int v = (t < NB) ? bsum[t] : 0;
    s[t] = v;
    __syncthreads();
    for (int off = 1; off < 128; off <<= 1) {
        int add = (t >= off) ? s[t - off] : 0;
        __syncthreads();
        s[t] += add;
        __syncthreads();
    }
    if (t < NB) bsum[t] = s[t] - v;  // exclusive
    if (t == 127) *total = s[127];
}

__global__ void scan3_kernel(int* __restrict__ excl, const int* __restrict__ bsum, int N) {
    int i = blockIdx.x * blockDim.x + threadIdx.x;
    if (i < N) excl[i] += bsum[i >> 10];   // SCAN_BS = 1024
}

// ---------------- scatter edges into CSR slots ----------------
__global__ void scatter_kernel(const int* __restrict__ src, const int* __restrict__ dst,
                               const float* __restrict__ w, const int* __restrict__ row_start,
                               int* __restrict__ fill, int* __restrict__ col,
                               float* __restrict__ val, int E) {
    int e = blockIdx.x * blockDim.x + threadIdx.x;
    if (e >= E) return;
    float wv = w[e];
    if (wv == 0.0f) return;
    int d = dst[e];
    int pos = row_start[d] + atomicAdd(&fill[d], 1);
    col[pos] = src[e];
    val[pos] = wv;
}

// ---- prepB: arrange Bcat = [W2 | W1 | W0-W2] (FI x 3FO) into MFMA B-fragment layout ----
// Bfrag[t][s][lane][j] (bf16), t = n-tile (16 cols), s = k-step (32 k),
// element (k,n): lane = ((k%32)/8)*16 + (n%16), j = k%8.
template <int FI, int FO>
__global__ void prepB_kernel(const float* __restrict__ W, unsigned short* __restrict__ Bfrag) {
    constexpr int NT = 3 * FO / 16;
    constexpr int NS = FI / 32;
    int id = blockIdx.x * blockDim.x + threadIdx.x;
    if (id >= NT * NS * 64) return;
    int lane = id & 63;
    int s = (id >> 6) % NS;
    int t = (id >> 6) / NS;
    int n = t * 16 + (lane & 15);
    int kbase = s * 32 + (lane >> 4) * 8;
    int sec = n / FO;        // 0 -> W2, 1 -> W1, 2 -> W0 - W2
    int nc  = n % FO;
    ushort8_t out;
#pragma unroll
    for (int j = 0; j < 8; j++) {
        int k = kbase + j;
        float v;
        if (sec == 0)      v = W[(size_t)(2 * FI + k) * FO + nc];
        else if (sec == 1) v = W[(size_t)(1 * FI + k) * FO + nc];
        else               v = W[(size_t)(0 * FI + k) * FO + nc]
                             - W[(size_t)(2 * FI + k) * FO + nc];
        out[j] = f2bf(v);
    }
    *(ushort8_t*)(Bfrag + (size_t)id * 8) = out;
}

// ---- MFMA gemm3: Ubf = bf16(x@W2), T = x@W1, S = x@(W0-W2) ----
// No LDS, no barriers. 4 waves/block, wave = 16-row m-tile, full N = 3*FO.
// A frags loaded straight from global x (fp32 -> bf16 in regs), B frags from
// prepB's fragment-layout buffer (L1/L2-hot, 16B/lane coalesced).
template <int FI, int FO>
__global__ __launch_bounds__(256) void gemmM_kernel(
        const float* __restrict__ x, const unsigned short* __restrict__ Bfrag,
        float* __restrict__ T, float* __restrict__ S,
        unsigned short* __restrict__ Ubf, int N) {
    constexpr int NT = 3 * FO / 16;   // n-tiles
    constexpr int NS = FI / 32;       // k-steps
    const int lane = threadIdx.x & 63;
    const int wave = threadIdx.x >> 6;
    const int m0   = blockIdx.x * 64 + wave * 16;
    if (m0 >= N) return;
    const int quad = lane >> 4;
    const int mrow = m0 + (lane & 15);

    floatx4_t acc[NT];
#pragma unroll
    for (int t = 0; t < NT; t++) acc[t] = (floatx4_t){0.f, 0.f, 0.f, 0.f};

#pragma unroll
    for (int s = 0; s < NS; s++) {
        bf16x8_t a;
        if (mrow < N) {
            const float* ap = x + (size_t)mrow * FI + s * 32 + quad * 8;
            float4 a0 = *(const float4*)(ap);
            float4 a1 = *(const float4*)(ap + 4);
            a[0] = (short)f2bf(a0.x); a[1] = (short)f2bf(a0.y);
            a[2] = (short)f2bf(a0.z); a[3] = (short)f2bf(a0.w);
            a[4] = (short)f2bf(a1.x); a[5] = (short)f2bf(a1.y);
            a[6] = (short)f2bf(a1.z); a[7] = (short)f2bf(a1.w);
        } else {
            a = (bf16x8_t){0, 0, 0, 0, 0, 0, 0, 0};
        }
#pragma unroll
        for (int t = 0; t < NT; t++) {
            bf16x8_t b = *(const bf16x8_t*)(Bfrag + ((size_t)(t * NS + s) * 64 + lane) * 8);
            acc[t] = __builtin_amdgcn_mfma_f32_16x16x32_bf16(a, b, acc[t], 0, 0, 0);
        }
    }
    // C/D layout: col = lane&15, row = quad*4 + reg   [verified m89/m91]
#pragma unroll
    for (int t = 0; t < NT; t++) {
        int n   = t * 16 + (lane & 15);
        int sec = (t * 16) / FO;          // compile-time per t (FO multiple of 16)
        int nc  = n % FO;
#pragma unroll
        for (int r = 0; r < 4; r++) {
            int m = m0 + quad * 4 + r;
            if (m >= N) continue;
            float v = acc[t][r];
            size_t o = (size_t)m * FO + nc;
            if (sec == 0)      Ubf[o] = f2bf(v);
            else if (sec == 1) T[o] = v;
            else               S[o] = v;
        }
    }
}

// ---- propA8: Obf[i] = bf16( T[i] + 2 * sum_p val[p]*Ubf[col[p]] ) ----
// Thread per (row, 8-feature chunk); loop over the row's CSR range.
template <int FO>
__global__ void propA8_kernel(const unsigned short* __restrict__ Ubf,
                              const float* __restrict__ T,
                              const int* __restrict__ rs, const int* __restrict__ col,
                              const float* __restrict__ val,
                              unsigned short* __restrict__ Obf, int N) {
    constexpr int PER = FO / 8;
    unsigned idx = blockIdx.x * blockDim.x + threadIdx.x;
    if (idx >= (unsigned)N * PER) return;
    int i = idx / PER;
    int c = (idx & (PER - 1)) * 8;
    int beg = rs[i], end = rs[i + 1];
    float acc[8] = {0.f, 0.f, 0.f, 0.f, 0.f, 0.f, 0.f, 0.f};
    for (int p = beg; p < end; ++p) {
        float wv = val[p];
        int s = col[p];
        ushort8_t u = *(const ushort8_t*)(Ubf + (size_t)s * FO + c);
#pragma unroll
        for (int j = 0; j < 8; j++) acc[j] = fmaf(wv, bf2f(u[j]), acc[j]);
    }
    const float* tr = T + (size_t)i * FO + c;
    float4 t0 = *(const float4*)(tr);
    float4 t1 = *(const float4*)(tr + 4);
    const float ts[8] = {t0.x, t0.y, t0.z, t0.w, t1.x, t1.y, t1.z, t1.w};
    ushort8_t o;
#pragma unroll
    for (int j = 0; j < 8; j++) o[j] = f2bf(ts[j] + 2.f * acc[j]);
    *(ushort8_t*)(Obf + (size_t)i * FO + c) = o;
}

// ---- propC8: h[i] = leaky_relu(BN(S[i] + sum_p val[p]*Bbf[col[p]] + b))  (h may == S) ----
template <int FO>
__global__ void propC8_kernel(const unsigned short* __restrict__ Bbf,
                              const float* __restrict__ S,
                              const int* __restrict__ rs, const int* __restrict__ col,
                              const float* __restrict__ val,
                              const float* __restrict__ b, const float* __restrict__ g,
                              const float* __restrict__ be, const float* __restrict__ m,
                              const float* __restrict__ vv, float* __restrict__ h, int N) {
    constexpr int PER = FO / 8;
    unsigned idx = blockIdx.x * blockDim.x + threadIdx.x;
    if (idx >= (unsigned)N * PER) return;
    int i = idx / PER;
    int c = (idx & (PER - 1)) * 8;
    int beg = rs[i], end = rs[i + 1];
    float acc[8] = {0.f, 0.f, 0.f, 0.f, 0.f, 0.f, 0.f, 0.f};
    for (int p = beg; p < end; ++p) {
        float wv = val[p];
        int s = col[p];
        ushort8_t u = *(const ushort8_t*)(Bbf + (size_t)s * FO + c);
#pragma unroll
        for (int j = 0; j < 8; j++) acc[j] = fmaf(wv, bf2f(u[j]), acc[j]);
    }
    const float* sr = S + (size_t)i * FO + c;
    float4 s0 = *(const float4*)(sr);
    float4 s1 = *(const float4*)(sr + 4);
    const float ss[8] = {s0.x, s0.y, s0.z, s0.w, s1.x, s1.y, s1.z, s1.w};
    float out[8];
#pragma unroll
    for (int j = 0; j < 8; j++) {
        int f = c + j;
        float A = g[f] * rsqrtf(vv[f] + BN_EPS);
        float B = be[f] - (m[f] - b[f]) * A;
        float y = (ss[j] + acc[j]) * A + B;
        out[j] = y > 0.0f ? y : 0.01f * y;
    }
    float* hr = h + (size_t)i * FO + c;
    *(float4*)(hr)     = make_float4(out[0], out[1], out[2], out[3]);
    *(float4*)(hr + 4) = make_float4(out[4], out[5], out[6], out[7]);
}

// ---------------- mean pool: register accum + LDS table + few global atomics ----------------
__global__ void pool2_kernel(const float* __restrict__ h, const int* __restrict__ batch,
                             float* __restrict__ pool, float* __restrict__ cnt, int N) {
    __shared__ float sp[NG * 16];
    __shared__ float sc[NG];
    int t = threadIdx.x;
    for (int i = t; i < NG * 16; i += BS) sp[i] = 0.f;
    for (int i = t; i < NG; i += BS) sc[i] = 0.f;
    __syncthreads();
    int f = t & 15, lane = t >> 4;   // 16 lanes x 16 features
    int base = blockIdx.x * PNPB;
    int nEnd = min(base + PNPB, N);
    float acc = 0.f, cacc = 0.f;
    int gcur = -1;
    for (int n = base + lane; n < nEnd; n += 16) {
        int g = batch[n];
        if (g != gcur) {
            if (gcur >= 0) {
                atomicAdd(&sp[gcur * 16 + f], acc);
                if (f == 0) atomicAdd(&sc[gcur], cacc);
            }
            gcur = g; acc = 0.f; cacc = 0.f;
        }
        acc += h[(size_t)n * 16 + f];
        cacc += 1.f;
    }
    if (gcur >= 0) {
        atomicAdd(&sp[gcur * 16 + f], acc);
        if (f == 0) atomicAdd(&sc[gcur], cacc);
    }
    __syncthreads();
    for (int i = t; i < NG * 16; i += BS)
        if (sp[i] != 0.f) unsafeAtomicAdd(&pool[i], sp[i]);
    for (int i = t; i < NG; i += BS)
        if (sc[i] != 0.f) unsafeAtomicAdd(&cnt[i], sc[i]);
}

// ---------------- final linear head ----------------
__global__ void final_kernel(const float* __restrict__ pool, const float* __restrict__ cnt,
                             const float* __restrict__ lw, const float* __restrict__ lb,
                             float* __restrict__ out) {
    int idx = threadIdx.x;
    if (idx >= NG * 2) return;
    int g = idx >> 1;
    int c = idx & 1;
    float inv = 1.0f / fmaxf(cnt[g], 1.0f);
    float acc = 0.0f;
#pragma unroll
    for (int f = 0; f < 16; f++) acc += pool[g * 16 + f] * lw[c * 16 + f];
    out[idx] = acc * inv + lb[c];
}

extern "C" void kernel_launch(void* const* d_in, const int* in_sizes, int n_in,
                              void* d_out, int out_size, void* d_ws, size_t ws_size,
                              hipStream_t stream) {
    const float* x    = (const float*)d_in[0];
    const int*   ei   = (const int*)d_in[1];
    const int*   batch= (const int*)d_in[2];
    const float* W1 = (const float*)d_in[3];
    const float* b1 = (const float*)d_in[4];
    const float* g1 = (const float*)d_in[5];
    const float* be1= (const float*)d_in[6];
    const float* m1 = (const float*)d_in[7];
    const float* v1 = (const float*)d_in[8];
    const float* W2 = (const float*)d_in[9];
    const float* b2 = (const float*)d_in[10];
    const float* g2 = (const float*)d_in[11];
    const float* be2= (const float*)d_in[12];
    const float* m2 = (const float*)d_in[13];
    const float* v2 = (const float*)d_in[14];
    const float* W3 = (const float*)d_in[15];
    const float* b3 = (const float*)d_in[16];
    const float* g3 = (const float*)d_in[17];
    const float* be3= (const float*)d_in[18];
    const float* m3 = (const float*)d_in[19];
    const float* v3 = (const float*)d_in[20];
    const float* lw = (const float*)d_in[21];
    const float* lb = (const float*)d_in[22];

    const int* src = ei;            // edge_index[0]
    const int* dst = ei + NE;       // edge_index[1]

    float* ws = (float*)d_ws;
    // ---- workspace layout (4-byte units, 16B-aligned) ----
    size_t off = 0;
    float* deg   = ws + off; off += NN;
    int*   cnt_n = (int*)(ws + off); off += NN;
    int*   fill  = (int*)(ws + off); off += NN;
    float* pool  = ws + off; off += NG * 16;
    float* cnt   = ws + off; off += NG;
    size_t zero_bytes = off * sizeof(float);       // one memset covers all of the above
    float* w     = ws + off; off += NE;
    int*   rs    = (int*)(ws + off); off += NN + 4;  // row_start [N+1], padded
    int*   col   = (int*)(ws + off); off += NE;
    float* val   = ws + off; off += NE;
    int*   bsum  = (int*)(ws + off); off += 128;
    float* A    = ws + off; off += (size_t)NN * 64;          // T buffers
    float* Bb   = ws + off; off += (size_t)NN * 64;          // S1 / h1
    float* D    = ws + off; off += (size_t)NN * 32;          // S2 / h2
    float* C16  = ws + off; off += (size_t)NN * 16;          // S3 / h3
    unsigned short* Ubf  = (unsigned short*)(ws + off); off += (size_t)NN * 32;  // NN*64 bf16
    unsigned short* Bbbf = (unsigned short*)(ws + off); off += (size_t)NN * 32;  // NN*64 bf16

    // B-fragment buffers overlay `deg` (dead after wgt_hist): 49+12+3 KB << 400 KB
    unsigned short* Bf1 = (unsigned short*)deg;              // 12*4*64*8 = 24576 bf16
    unsigned short* Bf2 = Bf1 + 12 * 4 * 64 * 8;             //  6*2*64*8 =  6144 bf16
    unsigned short* Bf3 = Bf2 + 6 * 2 * 64 * 8;              //  3*1*64*8 =  1536 bf16

    hipMemsetAsync(ws, 0, zero_bytes, stream);

    // ---- edge weights + CSR build ----
    deg_kernel<<<cdiv(NE, BS), BS, 0, stream>>>(src, dst, deg, NE);
    wgt_hist_kernel<<<cdiv(NE, BS), BS, 0, stream>>>(src, dst, deg, w, cnt_n, NE);
    // deg now dead -> overlay Bfrag buffers
    prepB_kernel<128, 64><<<cdiv(12 * 4 * 64, BS), BS, 0, stream>>>(W1, Bf1);
    prepB_kernel<64, 32><<<cdiv(6 * 2 * 64, BS), BS, 0, stream>>>(W2, Bf2);
    prepB_kernel<32, 16><<<cdiv(3 * 1 * 64, BS), BS, 0, stream>>>(W3, Bf3);
    scan1_kernel<<<NB_SCAN, SCAN_BS, 0, stream>>>(cnt_n, rs, bsum, NN);
    scan2_kernel<<<1, 128, 0, stream>>>(bsum, rs + NN, NB_SCAN);
    scan3_kernel<<<cdiv(NN, BS), BS, 0, stream>>>(rs, bsum, NN);
    scatter_kernel<<<cdiv(NE, BS), BS, 0, stream>>>(src, dst, w, rs, fill, col, val, NE);

    // ---- layer 1: 128 -> 64 ----
    gemmM_kernel<128, 64><<<cdiv(NN, 64), 256, 0, stream>>>(x, Bf1, A, Bb, Ubf, NN);
    propA8_kernel<64><<<cdiv((long long)NN * 8, BS), BS, 0, stream>>>(Ubf, A, rs, col, val, Bbbf, NN);
    propC8_kernel<64><<<cdiv((long long)NN * 8, BS), BS, 0, stream>>>(Bbbf, Bb, rs, col, val,
                                                                      b1, g1, be1, m1, v1, Bb, NN);
    // ---- layer 2: 64 -> 32 ----
    gemmM_kernel<64, 32><<<cdiv(NN, 64), 256, 0, stream>>>(Bb, Bf2, A, D, Ubf, NN);
    propA8_kernel<32><<<cdiv((long long)NN * 4, BS), BS, 0, stream>>>(Ubf, A, rs, col, val, Bbbf, NN);
    propC8_kernel<32><<<cdiv((long long)NN * 4, BS), BS, 0, stream>>>(Bbbf, D, rs, col, val,
                                                                      b2, g2, be2, m2, v2, D, NN);
    // ---- layer 3: 32 -> 16 ----
    gemmM_kernel<32, 16><<<cdiv(NN, 64), 256, 0, stream>>>(D, Bf3, A, C16, Ubf, NN);
    propA8_kernel<16><<<cdiv((long long)NN * 2, BS), BS, 0, stream>>>(Ubf, A, rs, col, val, Bbbf, NN);
    propC8_kernel<16><<<cdiv((long long)NN * 2, BS), BS, 0, stream>>>(Bbbf, C16, rs, col, val,
                                                                      b3, g3, be3, m3, v3, C16, NN);
    // ---- pool + head ----
    pool2_kernel<<<cdiv(NN, PNPB), BS, 0, stream>>>(C16, batch, pool, cnt, NN);
    final_kernel<<<1, 128, 0, stream>>>(pool, cnt, lw, lb, (float*)d_out);
}

// Round 7
// 440.331 us; speedup vs baseline: 1.5124x; 1.1344x over previous
//
#include <hip/hip_runtime.h>
#include <hip/hip_bf16.h>

// Problem constants (match reference)
#define NN 100000   // nodes
#define NE 640000   // edges
#define NG 64       // graphs
#define BN_EPS 1e-5f

#define BS 256      // block size
#define SCAN_BS 1024
#define NB_SCAN ((NN + SCAN_BS - 1) / SCAN_BS)   // 98
#define PNPB 256    // nodes per block in pool (391 blocks -> full chip; R6's 2048/49-block version was 1.8%-occupancy latency-bound at 66us)

typedef __attribute__((ext_vector_type(8))) unsigned short ushort8_t;
typedef __attribute__((ext_vector_type(4))) unsigned short ushort4_t;
typedef __attribute__((ext_vector_type(8))) short bf16x8_t;    // MFMA A/B frag (4 VGPR)
typedef __attribute__((ext_vector_type(4))) float floatx4_t;   // MFMA C/D frag

static inline int cdiv(long long a, int b) { return (int)((a + b - 1) / b); }

__device__ __forceinline__ float bf2f(unsigned short u) {
    union { unsigned int i; float f; } c; c.i = ((unsigned int)u) << 16; return c.f;
}
__device__ __forceinline__ unsigned short f2bf(float f) {   // RNE
    unsigned int u = __float_as_uint(f);
    u += 0x7fffu + ((u >> 16) & 1u);
    return (unsigned short)(u >> 16);
}

// ---------------- degree: deg[s] += 1 for non-self-loop edges ----------------
__global__ void deg_kernel(const int* __restrict__ src, const int* __restrict__ dst,
                           float* __restrict__ deg, int E) {
    int e = blockIdx.x * blockDim.x + threadIdx.x;
    if (e >= E) return;
    int s = src[e], d = dst[e];
    if (s != d) unsafeAtomicAdd(&deg[s], 1.0f);
}

// ---- edge weights + CSR histogram: w[e] = -dinv[src]*dinv[dst]; cnt_n[dst]++ if w!=0 ----
__global__ void wgt_hist_kernel(const int* __restrict__ src, const int* __restrict__ dst,
                                const float* __restrict__ deg, float* __restrict__ w,
                                int* __restrict__ cnt_n, int E) {
    int e = blockIdx.x * blockDim.x + threadIdx.x;
    if (e >= E) return;
    int s = src[e], d = dst[e];
    float wv = 0.0f;
    if (s != d) {
        float ds_ = deg[s], dd = deg[d];
        float a = ds_ > 0.0f ? rsqrtf(ds_) : 0.0f;
        float b = dd  > 0.0f ? rsqrtf(dd)  : 0.0f;
        wv = -a * b;
    }
    w[e] = wv;
    if (wv != 0.0f) atomicAdd(&cnt_n[d], 1);
}

// ---------------- 3-kernel exclusive scan of cnt_n -> row_start ----------------
__global__ void scan1_kernel(const int* __restrict__ cnt, int* __restrict__ excl,
                             int* __restrict__ bsum, int N) {
    __shared__ int s[SCAN_BS];
    int t = threadIdx.x;
    int i = blockIdx.x * SCAN_BS + t;
    int v = (i < N) ? cnt[i] : 0;
    s[t] = v;
    __syncthreads();
    for (int off = 1; off < SCAN_BS; off <<= 1) {
        int add = (t >= off) ? s[t - off] : 0;
        __syncthreads();
        s[t] += add;
        __syncthreads();
    }
    if (i < N) excl[i] = s[t] - v;   // exclusive
    if (t == SCAN_BS - 1) bsum[blockIdx.x] = s[t];
}

__global__ void scan2_kernel(int* __restrict__ bsum, int* __restrict__ total, int NB) {
    __shared__ int s[128];
    int t = threadIdx.x;
    int v = (t < NB) ? bsum[t] : 0;
    s[t] = v;
    __syncthreads();
    for (int off = 1; off < 128; off <<= 1) {
        int add = (t >= off) ? s[t - off] : 0;
        __syncthreads();
        s[t] += add;
        __syncthreads();
    }
    if (t < NB) bsum[t] = s[t] - v;  // exclusive
    if (t == 127) *total = s[127];
}

__global__ void scan3_kernel(int* __restrict__ excl, const int* __restrict__ bsum, int N) {
    int i = blockIdx.x * blockDim.x + threadIdx.x;
    if (i < N) excl[i] += bsum[i >> 10];   // SCAN_BS = 1024
}

// ---------------- scatter edges into CSR slots ----------------
__global__ void scatter_kernel(const int* __restrict__ src, const int* __restrict__ dst,
                               const float* __restrict__ w, const int* __restrict__ row_start,
                               int* __restrict__ fill, int* __restrict__ col,
                               float* __restrict__ val, int E) {
    int e = blockIdx.x * blockDim.x + threadIdx.x;
    if (e >= E) return;
    float wv = w[e];
    if (wv == 0.0f) return;
    int d = dst[e];
    int pos = row_start[d] + atomicAdd(&fill[d], 1);
    col[pos] = src[e];
    val[pos] = wv;
}

// ---- prepB: arrange Bcat = [W2 | W1 | W0-W2] (FI x 3FO) into MFMA B-fragment layout ----
// Bfrag[t][s][lane][j] (bf16), t = n-tile (16 cols), s = k-step (32 k),
// element (k,n): lane = ((k%32)/8)*16 + (n%16), j = k%8.
template <int FI, int FO>
__global__ void prepB_kernel(const float* __restrict__ W, unsigned short* __restrict__ Bfrag) {
    constexpr int NT = 3 * FO / 16;
    constexpr int NS = FI / 32;
    int id = blockIdx.x * blockDim.x + threadIdx.x;
    if (id >= NT * NS * 64) return;
    int lane = id & 63;
    int s = (id >> 6) % NS;
    int t = (id >> 6) / NS;
    int n = t * 16 + (lane & 15);
    int kbase = s * 32 + (lane >> 4) * 8;
    int sec = n / FO;        // 0 -> W2, 1 -> W1, 2 -> W0 - W2
    int nc  = n % FO;
    ushort8_t out;
#pragma unroll
    for (int j = 0; j < 8; j++) {
        int k = kbase + j;
        float v;
        if (sec == 0)      v = W[(size_t)(2 * FI + k) * FO + nc];
        else if (sec == 1) v = W[(size_t)(1 * FI + k) * FO + nc];
        else               v = W[(size_t)(0 * FI + k) * FO + nc]
                             - W[(size_t)(2 * FI + k) * FO + nc];
        out[j] = f2bf(v);
    }
    *(ushort8_t*)(Bfrag + (size_t)id * 8) = out;
}

// ---- MFMA gemm3: Ubf = bf16(x@W2), T = x@W1, S = x@(W0-W2) ----
// No LDS, no barriers. 4 waves/block, wave = 16-row m-tile, full N = 3*FO.
template <int FI, int FO>
__global__ __launch_bounds__(256) void gemmM_kernel(
        const float* __restrict__ x, const unsigned short* __restrict__ Bfrag,
        float* __restrict__ T, float* __restrict__ S,
        unsigned short* __restrict__ Ubf, int N) {
    constexpr int NT = 3 * FO / 16;   // n-tiles
    constexpr int NS = FI / 32;       // k-steps
    const int lane = threadIdx.x & 63;
    const int wave = threadIdx.x >> 6;
    const int m0   = blockIdx.x * 64 + wave * 16;
    if (m0 >= N) return;
    const int quad = lane >> 4;
    const int mrow = m0 + (lane & 15);

    floatx4_t acc[NT];
#pragma unroll
    for (int t = 0; t < NT; t++) acc[t] = (floatx4_t){0.f, 0.f, 0.f, 0.f};

#pragma unroll
    for (int s = 0; s < NS; s++) {
        bf16x8_t a;
        if (mrow < N) {
            const float* ap = x + (size_t)mrow * FI + s * 32 + quad * 8;
            float4 a0 = *(const float4*)(ap);
            float4 a1 = *(const float4*)(ap + 4);
            a[0] = (short)f2bf(a0.x); a[1] = (short)f2bf(a0.y);
            a[2] = (short)f2bf(a0.z); a[3] = (short)f2bf(a0.w);
            a[4] = (short)f2bf(a1.x); a[5] = (short)f2bf(a1.y);
            a[6] = (short)f2bf(a1.z); a[7] = (short)f2bf(a1.w);
        } else {
            a = (bf16x8_t){0, 0, 0, 0, 0, 0, 0, 0};
        }
#pragma unroll
        for (int t = 0; t < NT; t++) {
            bf16x8_t b = *(const bf16x8_t*)(Bfrag + ((size_t)(t * NS + s) * 64 + lane) * 8);
            acc[t] = __builtin_amdgcn_mfma_f32_16x16x32_bf16(a, b, acc[t], 0, 0, 0);
        }
    }
    // C/D layout: col = lane&15, row = quad*4 + reg   [verified m89/m91]
#pragma unroll
    for (int t = 0; t < NT; t++) {
        int n   = t * 16 + (lane & 15);
        int sec = (t * 16) / FO;          // compile-time per t (FO multiple of 16)
        int nc  = n % FO;
#pragma unroll
        for (int r = 0; r < 4; r++) {
            int m = m0 + quad * 4 + r;
            if (m >= N) continue;
            float v = acc[t][r];
            size_t o = (size_t)m * FO + nc;
            if (sec == 0)      Ubf[o] = f2bf(v);
            else if (sec == 1) T[o] = v;
            else               S[o] = v;
        }
    }
}

// ---- propA8: Obf[i] = bf16( T[i] + 2 * sum_p val[p]*Ubf[col[p]] ) ----
// Thread per (row, 8-feature chunk); loop over the row's CSR range.
template <int FO>
__global__ void propA8_kernel(const unsigned short* __restrict__ Ubf,
                              const float* __restrict__ T,
                              const int* __restrict__ rs, const int* __restrict__ col,
                              const float* __restrict__ val,
                              unsigned short* __restrict__ Obf, int N) {
    constexpr int PER = FO / 8;
    unsigned idx = blockIdx.x * blockDim.x + threadIdx.x;
    if (idx >= (unsigned)N * PER) return;
    int i = idx / PER;
    int c = (idx & (PER - 1)) * 8;
    int beg = rs[i], end = rs[i + 1];
    float acc[8] = {0.f, 0.f, 0.f, 0.f, 0.f, 0.f, 0.f, 0.f};
    for (int p = beg; p < end; ++p) {
        float wv = val[p];
        int s = col[p];
        ushort8_t u = *(const ushort8_t*)(Ubf + (size_t)s * FO + c);
#pragma unroll
        for (int j = 0; j < 8; j++) acc[j] = fmaf(wv, bf2f(u[j]), acc[j]);
    }
    const float* tr = T + (size_t)i * FO + c;
    float4 t0 = *(const float4*)(tr);
    float4 t1 = *(const float4*)(tr + 4);
    const float ts[8] = {t0.x, t0.y, t0.z, t0.w, t1.x, t1.y, t1.z, t1.w};
    ushort8_t o;
#pragma unroll
    for (int j = 0; j < 8; j++) o[j] = f2bf(ts[j] + 2.f * acc[j]);
    *(ushort8_t*)(Obf + (size_t)i * FO + c) = o;
}

// ---- propC8: h[i] = leaky_relu(BN(S[i] + sum_p val[p]*Bbf[col[p]] + b))  (h may == S) ----
template <int FO>
__global__ void propC8_kernel(const unsigned short* __restrict__ Bbf,
                              const float* __restrict__ S,
                              const int* __restrict__ rs, const int* __restrict__ col,
                              const float* __restrict__ val,
                              const float* __restrict__ b, const float* __restrict__ g,
                              const float* __restrict__ be, const float* __restrict__ m,
                              const float* __restrict__ vv, float* __restrict__ h, int N) {
    constexpr int PER = FO / 8;
    unsigned idx = blockIdx.x * blockDim.x + threadIdx.x;
    if (idx >= (unsigned)N * PER) return;
    int i = idx / PER;
    int c = (idx & (PER - 1)) * 8;
    int beg = rs[i], end = rs[i + 1];
    float acc[8] = {0.f, 0.f, 0.f, 0.f, 0.f, 0.f, 0.f, 0.f};
    for (int p = beg; p < end; ++p) {
        float wv = val[p];
        int s = col[p];
        ushort8_t u = *(const ushort8_t*)(Bbf + (size_t)s * FO + c);
#pragma unroll
        for (int j = 0; j < 8; j++) acc[j] = fmaf(wv, bf2f(u[j]), acc[j]);
    }
    const float* sr = S + (size_t)i * FO + c;
    float4 s0 = *(const float4*)(sr);
    float4 s1 = *(const float4*)(sr + 4);
    const float ss[8] = {s0.x, s0.y, s0.z, s0.w, s1.x, s1.y, s1.z, s1.w};
    float out[8];
#pragma unroll
    for (int j = 0; j < 8; j++) {
        int f = c + j;
        float A = g[f] * rsqrtf(vv[f] + BN_EPS);
        float B = be[f] - (m[f] - b[f]) * A;
        float y = (ss[j] + acc[j]) * A + B;
        out[j] = y > 0.0f ? y : 0.01f * y;
    }
    float* hr = h + (size_t)i * FO + c;
    *(float4*)(hr)     = make_float4(out[0], out[1], out[2], out[3]);
    *(float4*)(hr + 4) = make_float4(out[4], out[5], out[6], out[7]);
}

// ---- mean pool v3: thread = (node-lane, feature-quad); float4 loads; register
// accum flushed on graph change to LDS table; few global atomics per block ----
__global__ __launch_bounds__(256) void pool3_kernel(
        const float* __restrict__ h, const int* __restrict__ batch,
        float* __restrict__ pool, float* __restrict__ cnt, int N) {
    __shared__ float sp[NG * 16];
    __shared__ float sc[NG];
    int t = threadIdx.x;
    for (int i = t; i < NG * 16; i += 256) sp[i] = 0.f;
    for (int i = t; i < NG; i += 256) sc[i] = 0.f;
    __syncthreads();
    const int f4 = (t & 3) * 4;      // feature quad
    const int nl = t >> 2;           // node lane 0..63
    const int base = blockIdx.x * PNPB;
    const int nEnd = min(base + PNPB, N);
    float4 acc = make_float4(0.f, 0.f, 0.f, 0.f);
    float cacc = 0.f;
    int gcur = -1;
    for (int n = base + nl; n < nEnd; n += 64) {
        int g = batch[n];
        if (g != gcur) {
            if (gcur >= 0) {
                atomicAdd(&sp[gcur * 16 + f4 + 0], acc.x);
                atomicAdd(&sp[gcur * 16 + f4 + 1], acc.y);
                atomicAdd(&sp[gcur * 16 + f4 + 2], acc.z);
                atomicAdd(&sp[gcur * 16 + f4 + 3], acc.w);
                if (f4 == 0) atomicAdd(&sc[gcur], cacc);
            }
            gcur = g; acc = make_float4(0.f, 0.f, 0.f, 0.f); cacc = 0.f;
        }
        float4 hv = *(const float4*)(h + (size_t)n * 16 + f4);
        acc.x += hv.x; acc.y += hv.y; acc.z += hv.z; acc.w += hv.w;
        cacc += 1.f;
    }
    if (gcur >= 0) {
        atomicAdd(&sp[gcur * 16 + f4 + 0], acc.x);
        atomicAdd(&sp[gcur * 16 + f4 + 1], acc.y);
        atomicAdd(&sp[gcur * 16 + f4 + 2], acc.z);
        atomicAdd(&sp[gcur * 16 + f4 + 3], acc.w);
        if (f4 == 0) atomicAdd(&sc[gcur], cacc);
    }
    __syncthreads();
    for (int i = t; i < NG * 16; i += 256)
        if (sp[i] != 0.f) unsafeAtomicAdd(&pool[i], sp[i]);
    for (int i = t; i < NG; i += 256)
        if (sc[i] != 0.f) unsafeAtomicAdd(&cnt[i], sc[i]);
}

// ---------------- final linear head ----------------
__global__ void final_kernel(const float* __restrict__ pool, const float* __restrict__ cnt,
                             const float* __restrict__ lw, const float* __restrict__ lb,
                             float* __restrict__ out) {
    int idx = threadIdx.x;
    if (idx >= NG * 2) return;
    int g = idx >> 1;
    int c = idx & 1;
    float inv = 1.0f / fmaxf(cnt[g], 1.0f);
    float acc = 0.0f;
#pragma unroll
    for (int f = 0; f < 16; f++) acc += pool[g * 16 + f] * lw[c * 16 + f];
    out[idx] = acc * inv + lb[c];
}

extern "C" void kernel_launch(void* const* d_in, const int* in_sizes, int n_in,
                              void* d_out, int out_size, void* d_ws, size_t ws_size,
                              hipStream_t stream) {
    const float* x    = (const float*)d_in[0];
    const int*   ei   = (const int*)d_in[1];
    const int*   batch= (const int*)d_in[2];
    const float* W1 = (const float*)d_in[3];
    const float* b1 = (const float*)d_in[4];
    const float* g1 = (const float*)d_in[5];
    const float* be1= (const float*)d_in[6];
    const float* m1 = (const float*)d_in[7];
    const float* v1 = (const float*)d_in[8];
    const float* W2 = (const float*)d_in[9];
    const float* b2 = (const float*)d_in[10];
    const float* g2 = (const float*)d_in[11];
    const float* be2= (const float*)d_in[12];
    const float* m2 = (const float*)d_in[13];
    const float* v2 = (const float*)d_in[14];
    const float* W3 = (const float*)d_in[15];
    const float* b3 = (const float*)d_in[16];
    const float* g3 = (const float*)d_in[17];
    const float* be3= (const float*)d_in[18];
    const float* m3 = (const float*)d_in[19];
    const float* v3 = (const float*)d_in[20];
    const float* lw = (const float*)d_in[21];
    const float* lb = (const float*)d_in[22];

    const int* src = ei;            // edge_index[0]
    const int* dst = ei + NE;       // edge_index[1]

    float* ws = (float*)d_ws;
    // ---- workspace layout (4-byte units, 16B-aligned) ----
    size_t off = 0;
    float* deg   = ws + off; off += NN;
    int*   cnt_n = (int*)(ws + off); off += NN;
    int*   fill  = (int*)(ws + off); off += NN;
    float* pool  = ws + off; off += NG * 16;
    float* cnt   = ws + off; off += NG;
    size_t zero_bytes = off * sizeof(float);       // one memset covers all of the above
    float* w     = ws + off; off += NE;
    int*   rs    = (int*)(ws + off); off += NN + 4;  // row_start [N+1], padded
    int*   col   = (int*)(ws + off); off += NE;
    float* val   = ws + off; off += NE;
    int*   bsum  = (int*)(ws + off); off += 128;
    float* A    = ws + off; off += (size_t)NN * 64;          // T buffers
    float* Bb   = ws + off; off += (size_t)NN * 64;          // S1 / h1
    float* D    = ws + off; off += (size_t)NN * 32;          // S2 / h2
    float* C16  = ws + off; off += (size_t)NN * 16;          // S3 / h3
    unsigned short* Ubf  = (unsigned short*)(ws + off); off += (size_t)NN * 32;  // NN*64 bf16
    unsigned short* Bbbf = (unsigned short*)(ws + off); off += (size_t)NN * 32;  // NN*64 bf16

    // B-fragment buffers overlay `deg` (dead after wgt_hist): 49+12+3 KB << 400 KB
    unsigned short* Bf1 = (unsigned short*)deg;              // 12*4*64*8 = 24576 bf16
    unsigned short* Bf2 = Bf1 + 12 * 4 * 64 * 8;             //  6*2*64*8 =  6144 bf16
    unsigned short* Bf3 = Bf2 + 6 * 2 * 64 * 8;              //  3*1*64*8 =  1536 bf16

    hipMemsetAsync(ws, 0, zero_bytes, stream);

    // ---- edge weights + CSR build ----
    deg_kernel<<<cdiv(NE, BS), BS, 0, stream>>>(src, dst, deg, NE);
    wgt_hist_kernel<<<cdiv(NE, BS), BS, 0, stream>>>(src, dst, deg, w, cnt_n, NE);
    // deg now dead -> overlay Bfrag buffers
    prepB_kernel<128, 64><<<cdiv(12 * 4 * 64, BS), BS, 0, stream>>>(W1, Bf1);
    prepB_kernel<64, 32><<<cdiv(6 * 2 * 64, BS), BS, 0, stream>>>(W2, Bf2);
    prepB_kernel<32, 16><<<cdiv(3 * 1 * 64, BS), BS, 0, stream>>>(W3, Bf3);
    scan1_kernel<<<NB_SCAN, SCAN_BS, 0, stream>>>(cnt_n, rs, bsum, NN);
    scan2_kernel<<<1, 128, 0, stream>>>(bsum, rs + NN, NB_SCAN);
    scan3_kernel<<<cdiv(NN, BS), BS, 0, stream>>>(rs, bsum, NN);
    scatter_kernel<<<cdiv(NE, BS), BS, 0, stream>>>(src, dst, w, rs, fill, col, val, NE);

    // ---- layer 1: 128 -> 64 ----
    gemmM_kernel<128, 64><<<cdiv(NN, 64), 256, 0, stream>>>(x, Bf1, A, Bb, Ubf, NN);
    propA8_kernel<64><<<cdiv((long long)NN * 8, BS), BS, 0, stream>>>(Ubf, A, rs, col, val, Bbbf, NN);
    propC8_kernel<64><<<cdiv((long long)NN * 8, BS), BS, 0, stream>>>(Bbbf, Bb, rs, col, val,
                                                                      b1, g1, be1, m1, v1, Bb, NN);
    // ---- layer 2: 64 -> 32 ----
    gemmM_kernel<64, 32><<<cdiv(NN, 64), 256, 0, stream>>>(Bb, Bf2, A, D, Ubf, NN);
    propA8_kernel<32><<<cdiv((long long)NN * 4, BS), BS, 0, stream>>>(Ubf, A, rs, col, val, Bbbf, NN);
    propC8_kernel<32><<<cdiv((long long)NN * 4, BS), BS, 0, stream>>>(Bbbf, D, rs, col, val,
                                                                      b2, g2, be2, m2, v2, D, NN);
    // ---- layer 3: 32 -> 16 ----
    gemmM_kernel<32, 16><<<cdiv(NN, 64), 256, 0, stream>>>(D, Bf3, A, C16, Ubf, NN);
    propA8_kernel<16><<<cdiv((long long)NN * 2, BS), BS, 0, stream>>>(Ubf, A, rs, col, val, Bbbf, NN);
    propC8_kernel<16><<<cdiv((long long)NN * 2, BS), BS, 0, stream>>>(Bbbf, C16, rs, col, val,
                                                                      b3, g3, be3, m3, v3, C16, NN);
    // ---- pool + head ----
    pool3_kernel<<<cdiv(NN, PNPB), 256, 0, stream>>>(C16, batch, pool, cnt, NN);
    final_kernel<<<1, 128, 0, stream>>>(pool, cnt, lw, lb, (float*)d_out);
}